// Round 17
// baseline (120.817 us; speedup 1.0000x reference)
//
#include <hip/hip_runtime.h>

typedef _Float16 half8 __attribute__((ext_vector_type(8)));
typedef _Float16 half4v __attribute__((ext_vector_type(4)));
typedef __fp16 fp16x2 __attribute__((ext_vector_type(2)));
typedef float f32x4 __attribute__((ext_vector_type(4)));
typedef float f32x16 __attribute__((ext_vector_type(16)));
typedef float float4v __attribute__((ext_vector_type(4)));
typedef unsigned uint32x2 __attribute__((ext_vector_type(2)));

constexpr int NS = 4096;   // B*S rows
constexpr int E  = 1024;
constexpr int H  = 16;
constexpr int HD = 64;
constexpr int M  = 2048;
constexpr int HE = 1024;   // H*HD

__device__ __forceinline__ void gload16(const _Float16* g, _Float16* l) {
  __builtin_amdgcn_global_load_lds((__attribute__((address_space(1))) void*)g,
                                   (__attribute__((address_space(3))) void*)l, 16, 0, 0);
}

__device__ __forceinline__ float fexp2(float x) {
#if __has_builtin(__builtin_amdgcn_exp2f)
  return __builtin_amdgcn_exp2f(x);
#else
  return __expf(x * 0.6931471805599453f);
#endif
}

// pack two f32 -> one dword of 2 fp16 (RTZ)
__device__ __forceinline__ unsigned pkh(float a, float b) {
  fp16x2 t = __builtin_amdgcn_cvt_pkrtz(a, b);
  return __builtin_bit_cast(unsigned, t);
}

// lane<->lane+32 half-exchange
__device__ __forceinline__ uint32x2 pl32swap(unsigned a, unsigned b) {
#if __has_builtin(__builtin_amdgcn_permlane32_swap)
  return __builtin_amdgcn_permlane32_swap(a, b, false, false);
#else
  unsigned sa = (unsigned)__shfl_xor((int)a, 32, 64);
  unsigned sb = (unsigned)__shfl_xor((int)b, 32, 64);
  uint32x2 r;
  r.x = (threadIdx.x & 32) ? sb : a;
  r.y = (threadIdx.x & 32) ? b : sa;
  return r;
#endif
}

__device__ __forceinline__ half8 mk8(unsigned a, unsigned b, unsigned c, unsigned d) {
  union { unsigned u[4]; half8 h; } t;
  t.u[0] = a; t.u[1] = b; t.u[2] = c; t.u[3] = d;
  return t.h;
}

// ---------------- prep kernels ----------------

__global__ void cvt_f32_to_f16(const float* __restrict__ in, _Float16* __restrict__ out,
                               float scale) {
  int i = (blockIdx.x * 256 + threadIdx.x) * 4;
  float4v v = *(const float4v*)(in + i);
  half4v o = { (_Float16)(v[0] * scale), (_Float16)(v[1] * scale),
               (_Float16)(v[2] * scale), (_Float16)(v[3] * scale) };
  *(half4v*)(out + i) = o;
}

// in fp32 [batch][R][C] -> out fp16 [batch][C][R]
__global__ void transpose_cvt(const float* __restrict__ in, _Float16* __restrict__ out,
                              int R, int C) {
  __shared__ float tile[32][33];
  int b = blockIdx.z;
  in  += (size_t)b * R * C;
  out += (size_t)b * R * C;
  int c0 = blockIdx.x * 32, r0 = blockIdx.y * 32;
  int tx = threadIdx.x, ty = threadIdx.y;  // 32 x 8
#pragma unroll
  for (int i = 0; i < 4; ++i)
    tile[ty + 8 * i][tx] = in[(size_t)(r0 + ty + 8 * i) * C + c0 + tx];
  __syncthreads();
#pragma unroll
  for (int i = 0; i < 4; ++i)
    out[(size_t)(c0 + ty + 8 * i) * R + r0 + tx] = (_Float16)tile[tx][ty + 8 * i];
}

// two 1024x1024 transposes in one launch (z selects source)
__global__ void transpose_cvt2(const float* __restrict__ inA, const float* __restrict__ inB,
                               _Float16* __restrict__ outA, _Float16* __restrict__ outB) {
  __shared__ float tile[32][33];
  const float* in = blockIdx.z ? inB : inA;
  _Float16* out = blockIdx.z ? outB : outA;
  int c0 = blockIdx.x * 32, r0 = blockIdx.y * 32;
  int tx = threadIdx.x, ty = threadIdx.y;  // 32 x 8
#pragma unroll
  for (int i = 0; i < 4; ++i)
    tile[ty + 8 * i][tx] = in[(size_t)(r0 + ty + 8 * i) * 1024 + c0 + tx];
  __syncthreads();
#pragma unroll
  for (int i = 0; i < 4; ++i)
    out[(size_t)(c0 + ty + 8 * i) * 1024 + r0 + tx] = (_Float16)tile[tx][ty + 8 * i];
}

// ---------------- GEMM: C[M][N] = A[M][K] * Bt[N][K]^T, fp32 acc ----------------
// 128x64 tile, 4 waves (2x2), wave tile 64x32, K-step 32, 32x32x16 MFMA:
// 6 LDS b128 reads serve 4 MFMA (32cy matrix-pipe vs 40cy with 16x16x32).
// A staged as 32r x 16k chunks (lane: row=l31, k=hi*8 — attn-K-proven layout),
// B from Bt as 32n x 16k chunks (lane: col=l31, k=hi*8 — attn-Q-proven).
// Single-sync dbuf (r8-proven). grid 512. LDS 24 KB.

template <typename OUT_T>
__global__ __launch_bounds__(256, 4) void gemm_f16(
    const _Float16* __restrict__ A,   // [Mrows][K]
    const _Float16* __restrict__ Bt,  // [Ncols][K]
    const float* __restrict__ bias,   // [Ncols]
    OUT_T* __restrict__ C,            // [Mrows][Ncols]
    int Ncols, int K, float scale)
{
  __shared__ alignas(16) _Float16 Ab[2][8 * 512];  // 16 KB: chunk (mgrp*2+ks) = 32r x 16k
  __shared__ alignas(16) _Float16 Bb[2][4 * 512];  //  8 KB: chunk (ngrp*2+ks) = 32n x 16k
  const int tid = threadIdx.x;
  const int wave = tid >> 6, lane = tid & 63;
  const int l31 = lane & 31, hi = lane >> 5;

  const int nwg = gridDim.x;
  int wg = (blockIdx.x & 7) * (nwg >> 3) + (blockIdx.x >> 3);  // XCD swizzle (nwg%8==0)
  const int nbn = Ncols >> 6;
  const int mblk = wg / nbn, nblk = wg % nbn;

  // wave w stages A mgroup w (both ksubs) + B chunk w (ngrp=w>>1, ks=w&1)
  const _Float16* aS = A  + (size_t)(mblk * 128 + wave * 32 + l31) * K + hi * 8;
  const _Float16* bS = Bt + (size_t)(nblk * 64 + (wave >> 1) * 32 + l31) * K
                       + (wave & 1) * 16 + hi * 8;
  const int dOff = lane * 8;
  _Float16* aD0[2] = { &Ab[0][(wave * 2) * 512 + dOff], &Ab[1][(wave * 2) * 512 + dOff] };
  _Float16* aD1[2] = { &Ab[0][(wave * 2 + 1) * 512 + dOff], &Ab[1][(wave * 2 + 1) * 512 + dOff] };
  _Float16* bD[2]  = { &Bb[0][wave * 512 + dOff], &Bb[1][wave * 512 + dOff] };

  const int wr = wave >> 1, wc = wave & 1;  // 2x2 wave grid, wave tile 64x32
  f32x16 acc[2];
  acc[0] = (f32x16){0.f,0.f,0.f,0.f,0.f,0.f,0.f,0.f,0.f,0.f,0.f,0.f,0.f,0.f,0.f,0.f};
  acc[1] = acc[0];

#define GSTAGE(b, kk) {                      \
    gload16(aS + (kk),      aD0[b]);         \
    gload16(aS + (kk) + 16, aD1[b]);         \
    gload16(bS + (kk),      bD[b]); }

  GSTAGE(0, 0);
  const int nk = K >> 5;
  for (int kt = 0; kt < nk; ++kt) {
    __syncthreads();   // own tile-kt loads drained + all waves' loads visible
    if (kt + 1 < nk) GSTAGE((kt + 1) & 1, (kt + 1) * 32);
    const _Float16* Ac = &Ab[kt & 1][0];
    const _Float16* Bc = &Bb[kt & 1][0];
    half8 af[2][2], bf[2];
#pragma unroll
    for (int i = 0; i < 2; ++i)
#pragma unroll
      for (int s = 0; s < 2; ++s)
        af[i][s] = *(const half8*)(Ac + ((wr * 2 + i) * 2 + s) * 512 + lane * 8);
#pragma unroll
    for (int s = 0; s < 2; ++s)
      bf[s] = *(const half8*)(Bc + (wc * 2 + s) * 512 + lane * 8);
    __builtin_amdgcn_s_setprio(1);
#pragma unroll
    for (int s = 0; s < 2; ++s) {
      acc[0] = __builtin_amdgcn_mfma_f32_32x32x16_f16(af[0][s], bf[s], acc[0], 0, 0, 0);
      acc[1] = __builtin_amdgcn_mfma_f32_32x32x16_f16(af[1][s], bf[s], acc[1], 0, 0, 0);
    }
    __builtin_amdgcn_s_setprio(0);
  }
#undef GSTAGE

  const int row0 = mblk * 128 + wr * 64;
  const int col = nblk * 64 + wc * 32 + l31;
  const float bv = bias[col];
#pragma unroll
  for (int i = 0; i < 2; ++i)
#pragma unroll
    for (int r = 0; r < 16; ++r) {
      int row = row0 + i * 32 + (r & 3) + 8 * (r >> 2) + 4 * hi;
      C[(size_t)row * Ncols + col] = (OUT_T)(acc[i][r] * scale + bv);
    }
}

// ---------------- fused attention (M-split x2, 64 q/wave, in-register P) --------
// (byte-identical to r13/r16 — best measured 51.7 us; frozen)

__global__ __launch_bounds__(256, 2) void attn_fused(
    const _Float16* __restrict__ qh,    // [NS][HE]
    const _Float16* __restrict__ Kh,    // [H][M][HD]  (pre-scaled by log2 e)
    const _Float16* __restrict__ Vth,   // [H][HD][M]
    _Float16* __restrict__ Op0,         // [NS][HE] partial sum pV, half 0
    _Float16* __restrict__ Op1,         // [NS][HE] partial sum pV, half 1
    float* __restrict__ Spart)          // [2][NS][H] partial sum p
{
  __shared__ alignas(16) _Float16 Kb[2][4096];  // 16 KB: 2 subtiles x (32m x 64d)
  __shared__ alignas(16) _Float16 Vb[2][4096];  // 16 KB: 2 subtiles x (64d x 32m)

  int wg = (blockIdx.x & 7) * 64 + (blockIdx.x >> 3);  // 2 heads per XCD
  const int h = wg >> 5, half = (wg >> 4) & 1, qblk = wg & 15;
  const int m0 = half * 1024;
  const int tid = threadIdx.x;
  const int wave = tid >> 6, lane = tid & 63;
  const int l31 = lane & 31, hi = lane >> 5;
  const int s0 = qblk * 256 + wave * 64;

  // Q B-frags for both q-groups: lane holds Q[s0+g*32+l31][c*16 + hi*8 + j]
  half8 qf[2][4];
#pragma unroll
  for (int g = 0; g < 2; ++g) {
    const _Float16* qp = qh + (size_t)(s0 + g * 32 + l31) * HE + h * HD + hi * 8;
    qf[g][0] = *(const half8*)(qp);
    qf[g][1] = *(const half8*)(qp + 16);
    qf[g][2] = *(const half8*)(qp + 32);
    qf[g][3] = *(const half8*)(qp + 48);
  }

  const _Float16* kS = Kh + (size_t)h * M * HD
                       + (size_t)((wave >> 1) * 32 + l31) * HD + (wave & 1) * 32 + hi * 8;
  const _Float16* vS = Vth + (size_t)(h * HD + (wave & 1) * 32 + l31) * M
                       + (wave >> 1) * 32 + hi * 8;
  const int dOff = wave * 1024 + lane * 8;

  f32x16 accA[2], accB[2];
  float lsum[2] = {0.f, 0.f};
#pragma unroll
  for (int g = 0; g < 2; ++g) {
    accA[g] = (f32x16){0.f,0.f,0.f,0.f,0.f,0.f,0.f,0.f,0.f,0.f,0.f,0.f,0.f,0.f,0.f,0.f};
    accB[g] = (f32x16){0.f,0.f,0.f,0.f,0.f,0.f,0.f,0.f,0.f,0.f,0.f,0.f,0.f,0.f,0.f,0.f};
  }

#define STAGE(b, mm) {                                        \
    gload16(kS + (size_t)(mm) * HD,      &Kb[b][dOff]);       \
    gload16(kS + (size_t)(mm) * HD + 16, &Kb[b][dOff + 512]); \
    gload16(vS + (mm),                   &Vb[b][dOff]);       \
    gload16(vS + (mm) + 16,              &Vb[b][dOff + 512]); }

  STAGE(0, m0);
  for (int kt = 0; kt < 16; ++kt) {
    const int cur = kt & 1;
    __syncthreads();   // own tile-kt loads drained + all waves' loads visible
    if (kt < 15) STAGE(cur ^ 1, m0 + (kt + 1) * 64);

    const _Float16* Kc = &Kb[cur][0];
    const _Float16* Vc = &Vb[cur][0];
    half8 kf[8];
#pragma unroll
    for (int c = 0; c < 8; ++c) kf[c] = *(const half8*)(Kc + c * 512 + lane * 8);

    half8 paA0[2], paA1[2], paB0[2], paB1[2];
#pragma unroll
    for (int g = 0; g < 2; ++g) {
      f32x16 sA = (f32x16){0.f,0.f,0.f,0.f,0.f,0.f,0.f,0.f,0.f,0.f,0.f,0.f,0.f,0.f,0.f,0.f};
      f32x16 sB = sA;
      __builtin_amdgcn_s_setprio(1);
#pragma unroll
      for (int c = 0; c < 4; ++c)
        sA = __builtin_amdgcn_mfma_f32_32x32x16_f16(kf[c], qf[g][c], sA, 0, 0, 0);
#pragma unroll
      for (int c = 0; c < 4; ++c)
        sB = __builtin_amdgcn_mfma_f32_32x32x16_f16(kf[4 + c], qf[g][c], sB, 0, 0, 0);
      __builtin_amdgcn_s_setprio(0);

      unsigned pdA[8], pdB[8];
      float la = 0.f;
#pragma unroll
      for (int i = 0; i < 8; ++i) {
        float a0 = fexp2(sA[2 * i]);
        float a1 = fexp2(sA[2 * i + 1]);
        float b0 = fexp2(sB[2 * i]);
        float b1 = fexp2(sB[2 * i + 1]);
        la += (a0 + a1) + (b0 + b1);
        pdA[i] = pkh(a0, a1);
        pdB[i] = pkh(b0, b1);
      }
      lsum[g] += la;
      uint32x2 wA0 = pl32swap(pdA[0], pdA[2]);
      uint32x2 wA1 = pl32swap(pdA[1], pdA[3]);
      uint32x2 wA2 = pl32swap(pdA[4], pdA[6]);
      uint32x2 wA3 = pl32swap(pdA[5], pdA[7]);
      paA0[g] = mk8(wA0.x, wA1.x, wA0.y, wA1.y);
      paA1[g] = mk8(wA2.x, wA3.x, wA2.y, wA3.y);
      uint32x2 wB0 = pl32swap(pdB[0], pdB[2]);
      uint32x2 wB1 = pl32swap(pdB[1], pdB[3]);
      uint32x2 wB2 = pl32swap(pdB[4], pdB[6]);
      uint32x2 wB3 = pl32swap(pdB[5], pdB[7]);
      paB0[g] = mk8(wB0.x, wB1.x, wB0.y, wB1.y);
      paB1[g] = mk8(wB2.x, wB3.x, wB2.y, wB3.y);
    }

    // PV: V chunks read once, used by both q-groups
    {
      half8 v0 = *(const half8*)(Vc + lane * 8);
      half8 v1 = *(const half8*)(Vc + 512 + lane * 8);
      half8 v2 = *(const half8*)(Vc + 1024 + lane * 8);
      half8 v3 = *(const half8*)(Vc + 1536 + lane * 8);
      __builtin_amdgcn_s_setprio(1);
#pragma unroll
      for (int g = 0; g < 2; ++g) {
        accA[g] = __builtin_amdgcn_mfma_f32_32x32x16_f16(paA0[g], v0, accA[g], 0, 0, 0);
        accA[g] = __builtin_amdgcn_mfma_f32_32x32x16_f16(paA1[g], v1, accA[g], 0, 0, 0);
        accB[g] = __builtin_amdgcn_mfma_f32_32x32x16_f16(paA0[g], v2, accB[g], 0, 0, 0);
        accB[g] = __builtin_amdgcn_mfma_f32_32x32x16_f16(paA1[g], v3, accB[g], 0, 0, 0);
      }
      __builtin_amdgcn_s_setprio(0);
    }
    {
      half8 v0 = *(const half8*)(Vc + 2048 + lane * 8);
      half8 v1 = *(const half8*)(Vc + 2560 + lane * 8);
      half8 v2 = *(const half8*)(Vc + 3072 + lane * 8);
      half8 v3 = *(const half8*)(Vc + 3584 + lane * 8);
      __builtin_amdgcn_s_setprio(1);
#pragma unroll
      for (int g = 0; g < 2; ++g) {
        accA[g] = __builtin_amdgcn_mfma_f32_32x32x16_f16(paB0[g], v0, accA[g], 0, 0, 0);
        accA[g] = __builtin_amdgcn_mfma_f32_32x32x16_f16(paB1[g], v1, accA[g], 0, 0, 0);
        accB[g] = __builtin_amdgcn_mfma_f32_32x32x16_f16(paB0[g], v2, accB[g], 0, 0, 0);
        accB[g] = __builtin_amdgcn_mfma_f32_32x32x16_f16(paB1[g], v3, accB[g], 0, 0, 0);
      }
      __builtin_amdgcn_s_setprio(0);
    }
  }
#undef STAGE

  _Float16* Op = half ? Op1 : Op0;
  float* Sp = Spart + (size_t)half * (NS * H);
#pragma unroll
  for (int g = 0; g < 2; ++g) {
#pragma unroll
    for (int r = 0; r < 16; ++r) {
      int q = s0 + g * 32 + (r & 3) + 8 * (r >> 2) + 4 * hi;
      Op[(size_t)q * HE + h * HD + l31]      = (_Float16)accA[g][r];
      Op[(size_t)q * HE + h * HD + 32 + l31] = (_Float16)accB[g][r];
    }
    float tot = lsum[g] + __shfl_xor(lsum[g], 32, 64);
    if (hi == 0) Sp[(size_t)(s0 + g * 32 + l31) * H + h] = tot;
  }
}

// combine: attnh = (O0 + O1) / (S0 + S1)
__global__ void attn_combine(const _Float16* __restrict__ O0, const _Float16* __restrict__ O1,
                             const float* __restrict__ Spart, _Float16* __restrict__ out) {
  int idx = (blockIdx.x * 256 + threadIdx.x) * 8;
  int row = idx >> 10, he = idx & 1023, h = he >> 6;
  half8 a = *(const half8*)(O0 + idx);
  half8 b = *(const half8*)(O1 + idx);
  float s = Spart[(size_t)row * H + h] + Spart[(size_t)(NS + row) * H + h];
  float inv = 1.0f / s;
  half8 o;
#pragma unroll
  for (int j = 0; j < 8; ++j) o[j] = (_Float16)(((float)a[j] + (float)b[j]) * inv);
  *(half8*)(out + idx) = o;
}

// ---------------- launch ----------------

extern "C" void kernel_launch(void* const* d_in, const int* in_sizes, int n_in,
                              void* d_out, int out_size, void* d_ws, size_t ws_size,
                              hipStream_t stream) {
  const float* tensor = (const float*)d_in[0];
  const float* Wq     = (const float*)d_in[1];
  const float* bq     = (const float*)d_in[2];
  const float* Kp     = (const float*)d_in[3];
  const float* Vp     = (const float*)d_in[4];
  const float* Wd     = (const float*)d_in[5];
  const float* bd     = (const float*)d_in[6];
  float* out = (float*)d_out;

  char* ws = (char*)d_ws;
  _Float16* th    = (_Float16*)(ws);                  // [4096][1024] 8 MB; reused as Op0
  _Float16* qhb   = (_Float16*)(ws + (8  << 20));     // 8 MB
  _Float16* attnh = (_Float16*)(ws + (16 << 20));     // 8 MB
  _Float16* Wqt   = (_Float16*)(ws + (24 << 20));     // 2 MB; reused as Spart after gemm1
  _Float16* Wdt   = (_Float16*)(ws + (26 << 20));     // 2 MB
  _Float16* Khb   = (_Float16*)(ws + (28 << 20));     // 4 MB
  _Float16* Vth   = (_Float16*)(ws + (32 << 20));     // 4 MB
  _Float16* Op0   = (_Float16*)(ws);                  // overlays th (dead after gemm1)
  _Float16* Op1   = (_Float16*)(ws + (36 << 20));     // 8 MB  (total 44 MB)
  float*    Spart = (float*)(ws + (24 << 20));        // [2][4096][16] f32, overlays Wqt

  cvt_f32_to_f16<<<(NS * E) / 1024, 256, 0, stream>>>(tensor, th, 1.0f);
  cvt_f32_to_f16<<<(H * M * HD) / 1024, 256, 0, stream>>>(Kp, Khb, 1.44269504088896f);
  transpose_cvt2<<<dim3(32, 32, 2), dim3(32, 8), 0, stream>>>(Wq, Wd, Wqt, Wdt);
  transpose_cvt<<<dim3(2, 64, 16), dim3(32, 8), 0, stream>>>(Vp, Vth, 2048, 64);

  gemm_f16<_Float16><<<512, 256, 0, stream>>>(th, Wqt, bq, qhb, HE, E, 1.0f);
  attn_fused<<<512, 256, 0, stream>>>(qhb, Khb, Vth, Op0, Op1, Spart);
  attn_combine<<<(NS * HE) / 2048, 256, 0, stream>>>(Op0, Op1, Spart, attnh);
  gemm_f16<float><<<512, 256, 0, stream>>>(attnh, Wdt, bd, out, E, HE, 0.125f);
}

// Round 18
// 117.745 us; speedup vs baseline: 1.0261x; 1.0261x over previous
//
#include <hip/hip_runtime.h>

typedef _Float16 half8 __attribute__((ext_vector_type(8)));
typedef _Float16 half4v __attribute__((ext_vector_type(4)));
typedef __fp16 fp16x2 __attribute__((ext_vector_type(2)));
typedef float f32x4 __attribute__((ext_vector_type(4)));
typedef float f32x16 __attribute__((ext_vector_type(16)));
typedef float float4v __attribute__((ext_vector_type(4)));
typedef unsigned uint32x2 __attribute__((ext_vector_type(2)));

constexpr int NS = 4096;   // B*S rows
constexpr int E  = 1024;
constexpr int H  = 16;
constexpr int HD = 64;
constexpr int M  = 2048;
constexpr int HE = 1024;   // H*HD

__device__ __forceinline__ void gload16(const _Float16* g, _Float16* l) {
  __builtin_amdgcn_global_load_lds((__attribute__((address_space(1))) void*)g,
                                   (__attribute__((address_space(3))) void*)l, 16, 0, 0);
}

__device__ __forceinline__ float fexp2(float x) {
#if __has_builtin(__builtin_amdgcn_exp2f)
  return __builtin_amdgcn_exp2f(x);
#else
  return __expf(x * 0.6931471805599453f);
#endif
}

// pack two f32 -> one dword of 2 fp16 (RTZ)
__device__ __forceinline__ unsigned pkh(float a, float b) {
  fp16x2 t = __builtin_amdgcn_cvt_pkrtz(a, b);
  return __builtin_bit_cast(unsigned, t);
}

// lane<->lane+32 half-exchange
__device__ __forceinline__ uint32x2 pl32swap(unsigned a, unsigned b) {
#if __has_builtin(__builtin_amdgcn_permlane32_swap)
  return __builtin_amdgcn_permlane32_swap(a, b, false, false);
#else
  unsigned sa = (unsigned)__shfl_xor((int)a, 32, 64);
  unsigned sb = (unsigned)__shfl_xor((int)b, 32, 64);
  uint32x2 r;
  r.x = (threadIdx.x & 32) ? sb : a;
  r.y = (threadIdx.x & 32) ? b : sa;
  return r;
#endif
}

__device__ __forceinline__ half8 mk8(unsigned a, unsigned b, unsigned c, unsigned d) {
  union { unsigned u[4]; half8 h; } t;
  t.u[0] = a; t.u[1] = b; t.u[2] = c; t.u[3] = d;
  return t.h;
}

// ---------------- prep kernels ----------------

// two elementwise f32->f16 converts in one launch (block-index selects source)
__global__ void cvt_f32_to_f16_2(const float* __restrict__ inA, _Float16* __restrict__ outA,
                                 float scaleA, int nblkA,
                                 const float* __restrict__ inB, _Float16* __restrict__ outB,
                                 float scaleB) {
  const float* in;
  _Float16* out;
  float scale;
  int i;
  if (blockIdx.x < (unsigned)nblkA) {
    in = inA; out = outA; scale = scaleA;
    i = (blockIdx.x * 256 + threadIdx.x) * 4;
  } else {
    in = inB; out = outB; scale = scaleB;
    i = ((blockIdx.x - nblkA) * 256 + threadIdx.x) * 4;
  }
  float4v v = *(const float4v*)(in + i);
  half4v o = { (_Float16)(v[0] * scale), (_Float16)(v[1] * scale),
               (_Float16)(v[2] * scale), (_Float16)(v[3] * scale) };
  *(half4v*)(out + i) = o;
}

// in fp32 [batch][R][C] -> out fp16 [batch][C][R]
__global__ void transpose_cvt(const float* __restrict__ in, _Float16* __restrict__ out,
                              int R, int C) {
  __shared__ float tile[32][33];
  int b = blockIdx.z;
  in  += (size_t)b * R * C;
  out += (size_t)b * R * C;
  int c0 = blockIdx.x * 32, r0 = blockIdx.y * 32;
  int tx = threadIdx.x, ty = threadIdx.y;  // 32 x 8
#pragma unroll
  for (int i = 0; i < 4; ++i)
    tile[ty + 8 * i][tx] = in[(size_t)(r0 + ty + 8 * i) * C + c0 + tx];
  __syncthreads();
#pragma unroll
  for (int i = 0; i < 4; ++i)
    out[(size_t)(c0 + ty + 8 * i) * R + r0 + tx] = (_Float16)tile[tx][ty + 8 * i];
}

// two 1024x1024 transposes in one launch (z selects source)
__global__ void transpose_cvt2(const float* __restrict__ inA, const float* __restrict__ inB,
                               _Float16* __restrict__ outA, _Float16* __restrict__ outB) {
  __shared__ float tile[32][33];
  const float* in = blockIdx.z ? inB : inA;
  _Float16* out = blockIdx.z ? outB : outA;
  int c0 = blockIdx.x * 32, r0 = blockIdx.y * 32;
  int tx = threadIdx.x, ty = threadIdx.y;  // 32 x 8
#pragma unroll
  for (int i = 0; i < 4; ++i)
    tile[ty + 8 * i][tx] = in[(size_t)(r0 + ty + 8 * i) * 1024 + c0 + tx];
  __syncthreads();
#pragma unroll
  for (int i = 0; i < 4; ++i)
    out[(size_t)(c0 + ty + 8 * i) * 1024 + r0 + tx] = (_Float16)tile[tx][ty + 8 * i];
}

// ---------------- GEMM: C[M][N] = A[M][K] * Bt[N][K]^T, fp32 acc ----------------
// (r16-proven) 128x64 tile, 4 waves (2x2), wave tile 64x32 (4x2 frags):
// 6 LDS b128 reads serve 8 MFMA per K-step. Single-sync dbuf. grid 512.

template <typename OUT_T>
__global__ __launch_bounds__(256, 4) void gemm_f16(
    const _Float16* __restrict__ A,   // [Mrows][K]
    const _Float16* __restrict__ Bt,  // [Ncols][K]
    const float* __restrict__ bias,   // [Ncols]
    OUT_T* __restrict__ C,            // [Mrows][Ncols]
    int Ncols, int K, float scale)
{
  __shared__ alignas(16) _Float16 Ab[2][8 * 512];  // 16 KB: 8 chunks of 16r x 32k
  __shared__ alignas(16) _Float16 Bb[2][4 * 512];  //  8 KB: 4 chunks
  const int tid = threadIdx.x;
  const int wave = tid >> 6, lane = tid & 63;
  const int l15 = lane & 15, l4 = lane >> 4;

  const int nwg = gridDim.x;
  int wg = (blockIdx.x & 7) * (nwg >> 3) + (blockIdx.x >> 3);  // XCD swizzle (nwg%8==0)
  const int nbn = Ncols >> 6;
  const int mblk = wg / nbn, nblk = wg % nbn;

  // wave w stages A chunks {w, w+4} and B chunk w
  const _Float16* aS0 = A  + (size_t)(mblk * 128 + wave * 16 + l15) * K + l4 * 8;
  const _Float16* aS1 = aS0 + (size_t)64 * K;
  const _Float16* bS  = Bt + (size_t)(nblk * 64 + wave * 16 + l15) * K + l4 * 8;
  _Float16* aD0a = &Ab[0][wave * 512];
  _Float16* aD0b = &Ab[0][(wave + 4) * 512];
  _Float16* aD1a = &Ab[1][wave * 512];
  _Float16* aD1b = &Ab[1][(wave + 4) * 512];
  _Float16* bD0  = &Bb[0][wave * 512];
  _Float16* bD1  = &Bb[1][wave * 512];

  const int wr = wave >> 1, wc = wave & 1;  // 2x2 wave grid, wave tile 64x32
  f32x4 acc[4][2];
#pragma unroll
  for (int i = 0; i < 4; ++i)
#pragma unroll
    for (int n = 0; n < 2; ++n) acc[i][n] = (f32x4){0.f, 0.f, 0.f, 0.f};

  gload16(aS0, aD0a);
  gload16(aS1, aD0b);
  gload16(bS, bD0);
  aS0 += 32; aS1 += 32; bS += 32;

  const int nk = K >> 5;
  for (int kt = 0; kt < nk; ++kt) {
    __syncthreads();   // own tile-kt loads drained + all waves' loads visible
    if (kt + 1 < nk) {
      gload16(aS0, (kt & 1) ? aD0a : aD1a);
      gload16(aS1, (kt & 1) ? aD0b : aD1b);
      gload16(bS,  (kt & 1) ? bD0  : bD1);
      aS0 += 32; aS1 += 32; bS += 32;
    }
    const _Float16* Ac = (kt & 1) ? &Ab[1][0] : &Ab[0][0];
    const _Float16* Bc = (kt & 1) ? &Bb[1][0] : &Bb[0][0];
    half8 af[4], bf[2];
#pragma unroll
    for (int i = 0; i < 4; ++i) af[i] = *(const half8*)(Ac + (wr * 4 + i) * 512 + lane * 8);
#pragma unroll
    for (int n = 0; n < 2; ++n) bf[n] = *(const half8*)(Bc + (wc * 2 + n) * 512 + lane * 8);
    __builtin_amdgcn_s_setprio(1);
#pragma unroll
    for (int i = 0; i < 4; ++i)
#pragma unroll
      for (int n = 0; n < 2; ++n)
        acc[i][n] = __builtin_amdgcn_mfma_f32_16x16x32_f16(af[i], bf[n], acc[i][n], 0, 0, 0);
    __builtin_amdgcn_s_setprio(0);
  }

  const int row0 = mblk * 128 + wr * 64;
  const int col0 = nblk * 64 + wc * 32;
#pragma unroll
  for (int n = 0; n < 2; ++n) {
    int col = col0 + n * 16 + l15;
    float bv = bias[col];
#pragma unroll
    for (int i = 0; i < 4; ++i)
#pragma unroll
      for (int r = 0; r < 4; ++r) {
        int row = row0 + i * 16 + l4 * 4 + r;
        C[(size_t)row * Ncols + col] = (OUT_T)(acc[i][n][r] * scale + bv);
      }
  }
}

// ---------------- fused attention (M-split x2, 64 q/wave, in-register P) --------
// (byte-identical to r13/r16 — best measured 51.7 us; frozen)

__global__ __launch_bounds__(256, 2) void attn_fused(
    const _Float16* __restrict__ qh,    // [NS][HE]
    const _Float16* __restrict__ Kh,    // [H][M][HD]  (pre-scaled by log2 e)
    const _Float16* __restrict__ Vth,   // [H][HD][M]
    _Float16* __restrict__ Op0,         // [NS][HE] partial sum pV, half 0
    _Float16* __restrict__ Op1,         // [NS][HE] partial sum pV, half 1
    float* __restrict__ Spart)          // [2][NS][H] partial sum p
{
  __shared__ alignas(16) _Float16 Kb[2][4096];  // 16 KB: 2 subtiles x (32m x 64d)
  __shared__ alignas(16) _Float16 Vb[2][4096];  // 16 KB: 2 subtiles x (64d x 32m)

  int wg = (blockIdx.x & 7) * 64 + (blockIdx.x >> 3);  // 2 heads per XCD
  const int h = wg >> 5, half = (wg >> 4) & 1, qblk = wg & 15;
  const int m0 = half * 1024;
  const int tid = threadIdx.x;
  const int wave = tid >> 6, lane = tid & 63;
  const int l31 = lane & 31, hi = lane >> 5;
  const int s0 = qblk * 256 + wave * 64;

  // Q B-frags for both q-groups: lane holds Q[s0+g*32+l31][c*16 + hi*8 + j]
  half8 qf[2][4];
#pragma unroll
  for (int g = 0; g < 2; ++g) {
    const _Float16* qp = qh + (size_t)(s0 + g * 32 + l31) * HE + h * HD + hi * 8;
    qf[g][0] = *(const half8*)(qp);
    qf[g][1] = *(const half8*)(qp + 16);
    qf[g][2] = *(const half8*)(qp + 32);
    qf[g][3] = *(const half8*)(qp + 48);
  }

  const _Float16* kS = Kh + (size_t)h * M * HD
                       + (size_t)((wave >> 1) * 32 + l31) * HD + (wave & 1) * 32 + hi * 8;
  const _Float16* vS = Vth + (size_t)(h * HD + (wave & 1) * 32 + l31) * M
                       + (wave >> 1) * 32 + hi * 8;
  const int dOff = wave * 1024 + lane * 8;

  f32x16 accA[2], accB[2];
  float lsum[2] = {0.f, 0.f};
#pragma unroll
  for (int g = 0; g < 2; ++g) {
    accA[g] = (f32x16){0.f,0.f,0.f,0.f,0.f,0.f,0.f,0.f,0.f,0.f,0.f,0.f,0.f,0.f,0.f,0.f};
    accB[g] = (f32x16){0.f,0.f,0.f,0.f,0.f,0.f,0.f,0.f,0.f,0.f,0.f,0.f,0.f,0.f,0.f,0.f};
  }

#define STAGE(b, mm) {                                        \
    gload16(kS + (size_t)(mm) * HD,      &Kb[b][dOff]);       \
    gload16(kS + (size_t)(mm) * HD + 16, &Kb[b][dOff + 512]); \
    gload16(vS + (mm),                   &Vb[b][dOff]);       \
    gload16(vS + (mm) + 16,              &Vb[b][dOff + 512]); }

  STAGE(0, m0);
  for (int kt = 0; kt < 16; ++kt) {
    const int cur = kt & 1;
    __syncthreads();   // own tile-kt loads drained + all waves' loads visible
    if (kt < 15) STAGE(cur ^ 1, m0 + (kt + 1) * 64);

    const _Float16* Kc = &Kb[cur][0];
    const _Float16* Vc = &Vb[cur][0];
    half8 kf[8];
#pragma unroll
    for (int c = 0; c < 8; ++c) kf[c] = *(const half8*)(Kc + c * 512 + lane * 8);

    half8 paA0[2], paA1[2], paB0[2], paB1[2];
#pragma unroll
    for (int g = 0; g < 2; ++g) {
      f32x16 sA = (f32x16){0.f,0.f,0.f,0.f,0.f,0.f,0.f,0.f,0.f,0.f,0.f,0.f,0.f,0.f,0.f,0.f};
      f32x16 sB = sA;
      __builtin_amdgcn_s_setprio(1);
#pragma unroll
      for (int c = 0; c < 4; ++c)
        sA = __builtin_amdgcn_mfma_f32_32x32x16_f16(kf[c], qf[g][c], sA, 0, 0, 0);
#pragma unroll
      for (int c = 0; c < 4; ++c)
        sB = __builtin_amdgcn_mfma_f32_32x32x16_f16(kf[4 + c], qf[g][c], sB, 0, 0, 0);
      __builtin_amdgcn_s_setprio(0);

      unsigned pdA[8], pdB[8];
      float la = 0.f;
#pragma unroll
      for (int i = 0; i < 8; ++i) {
        float a0 = fexp2(sA[2 * i]);
        float a1 = fexp2(sA[2 * i + 1]);
        float b0 = fexp2(sB[2 * i]);
        float b1 = fexp2(sB[2 * i + 1]);
        la += (a0 + a1) + (b0 + b1);
        pdA[i] = pkh(a0, a1);
        pdB[i] = pkh(b0, b1);
      }
      lsum[g] += la;
      uint32x2 wA0 = pl32swap(pdA[0], pdA[2]);
      uint32x2 wA1 = pl32swap(pdA[1], pdA[3]);
      uint32x2 wA2 = pl32swap(pdA[4], pdA[6]);
      uint32x2 wA3 = pl32swap(pdA[5], pdA[7]);
      paA0[g] = mk8(wA0.x, wA1.x, wA0.y, wA1.y);
      paA1[g] = mk8(wA2.x, wA3.x, wA2.y, wA3.y);
      uint32x2 wB0 = pl32swap(pdB[0], pdB[2]);
      uint32x2 wB1 = pl32swap(pdB[1], pdB[3]);
      uint32x2 wB2 = pl32swap(pdB[4], pdB[6]);
      uint32x2 wB3 = pl32swap(pdB[5], pdB[7]);
      paB0[g] = mk8(wB0.x, wB1.x, wB0.y, wB1.y);
      paB1[g] = mk8(wB2.x, wB3.x, wB2.y, wB3.y);
    }

    // PV: V chunks read once, used by both q-groups
    {
      half8 v0 = *(const half8*)(Vc + lane * 8);
      half8 v1 = *(const half8*)(Vc + 512 + lane * 8);
      half8 v2 = *(const half8*)(Vc + 1024 + lane * 8);
      half8 v3 = *(const half8*)(Vc + 1536 + lane * 8);
      __builtin_amdgcn_s_setprio(1);
#pragma unroll
      for (int g = 0; g < 2; ++g) {
        accA[g] = __builtin_amdgcn_mfma_f32_32x32x16_f16(paA0[g], v0, accA[g], 0, 0, 0);
        accA[g] = __builtin_amdgcn_mfma_f32_32x32x16_f16(paA1[g], v1, accA[g], 0, 0, 0);
        accB[g] = __builtin_amdgcn_mfma_f32_32x32x16_f16(paA0[g], v2, accB[g], 0, 0, 0);
        accB[g] = __builtin_amdgcn_mfma_f32_32x32x16_f16(paA1[g], v3, accB[g], 0, 0, 0);
      }
      __builtin_amdgcn_s_setprio(0);
    }
    {
      half8 v0 = *(const half8*)(Vc + 2048 + lane * 8);
      half8 v1 = *(const half8*)(Vc + 2560 + lane * 8);
      half8 v2 = *(const half8*)(Vc + 3072 + lane * 8);
      half8 v3 = *(const half8*)(Vc + 3584 + lane * 8);
      __builtin_amdgcn_s_setprio(1);
#pragma unroll
      for (int g = 0; g < 2; ++g) {
        accA[g] = __builtin_amdgcn_mfma_f32_32x32x16_f16(paB0[g], v0, accA[g], 0, 0, 0);
        accA[g] = __builtin_amdgcn_mfma_f32_32x32x16_f16(paB1[g], v1, accA[g], 0, 0, 0);
        accB[g] = __builtin_amdgcn_mfma_f32_32x32x16_f16(paB0[g], v2, accB[g], 0, 0, 0);
        accB[g] = __builtin_amdgcn_mfma_f32_32x32x16_f16(paB1[g], v3, accB[g], 0, 0, 0);
      }
      __builtin_amdgcn_s_setprio(0);
    }
  }
#undef STAGE

  _Float16* Op = half ? Op1 : Op0;
  float* Sp = Spart + (size_t)half * (NS * H);
#pragma unroll
  for (int g = 0; g < 2; ++g) {
#pragma unroll
    for (int r = 0; r < 16; ++r) {
      int q = s0 + g * 32 + (r & 3) + 8 * (r >> 2) + 4 * hi;
      Op[(size_t)q * HE + h * HD + l31]      = (_Float16)accA[g][r];
      Op[(size_t)q * HE + h * HD + 32 + l31] = (_Float16)accB[g][r];
    }
    float tot = lsum[g] + __shfl_xor(lsum[g], 32, 64);
    if (hi == 0) Sp[(size_t)(s0 + g * 32 + l31) * H + h] = tot;
  }
}

// combine: attnh = (O0 + O1) / (S0 + S1)
__global__ void attn_combine(const _Float16* __restrict__ O0, const _Float16* __restrict__ O1,
                             const float* __restrict__ Spart, _Float16* __restrict__ out) {
  int idx = (blockIdx.x * 256 + threadIdx.x) * 8;
  int row = idx >> 10, he = idx & 1023, h = he >> 6;
  half8 a = *(const half8*)(O0 + idx);
  half8 b = *(const half8*)(O1 + idx);
  float s = Spart[(size_t)row * H + h] + Spart[(size_t)(NS + row) * H + h];
  float inv = 1.0f / s;
  half8 o;
#pragma unroll
  for (int j = 0; j < 8; ++j) o[j] = (_Float16)(((float)a[j] + (float)b[j]) * inv);
  *(half8*)(out + idx) = o;
}

// ---------------- launch ----------------

extern "C" void kernel_launch(void* const* d_in, const int* in_sizes, int n_in,
                              void* d_out, int out_size, void* d_ws, size_t ws_size,
                              hipStream_t stream) {
  const float* tensor = (const float*)d_in[0];
  const float* Wq     = (const float*)d_in[1];
  const float* bq     = (const float*)d_in[2];
  const float* Kp     = (const float*)d_in[3];
  const float* Vp     = (const float*)d_in[4];
  const float* Wd     = (const float*)d_in[5];
  const float* bd     = (const float*)d_in[6];
  float* out = (float*)d_out;

  char* ws = (char*)d_ws;
  _Float16* th    = (_Float16*)(ws);                  // [4096][1024] 8 MB; reused as Op0
  _Float16* qhb   = (_Float16*)(ws + (8  << 20));     // 8 MB
  _Float16* attnh = (_Float16*)(ws + (16 << 20));     // 8 MB
  _Float16* Wqt   = (_Float16*)(ws + (24 << 20));     // 2 MB; reused as Spart after gemm1
  _Float16* Wdt   = (_Float16*)(ws + (26 << 20));     // 2 MB
  _Float16* Khb   = (_Float16*)(ws + (28 << 20));     // 4 MB
  _Float16* Vth   = (_Float16*)(ws + (32 << 20));     // 4 MB
  _Float16* Op0   = (_Float16*)(ws);                  // overlays th (dead after gemm1)
  _Float16* Op1   = (_Float16*)(ws + (36 << 20));     // 8 MB  (total 44 MB)
  float*    Spart = (float*)(ws + (24 << 20));        // [2][4096][16] f32, overlays Wqt

  constexpr int nblkT = (NS * E) / 1024;        // 4096
  constexpr int nblkK = (H * M * HD) / 1024;    // 2048
  cvt_f32_to_f16_2<<<nblkT + nblkK, 256, 0, stream>>>(
      tensor, th, 1.0f, nblkT, Kp, Khb, 1.44269504088896f);
  transpose_cvt2<<<dim3(32, 32, 2), dim3(32, 8), 0, stream>>>(Wq, Wd, Wqt, Wdt);
  transpose_cvt<<<dim3(2, 64, 16), dim3(32, 8), 0, stream>>>(Vp, Vth, 2048, 64);

  gemm_f16<_Float16><<<512, 256, 0, stream>>>(th, Wqt, bq, qhb, HE, E, 1.0f);
  attn_fused<<<512, 256, 0, stream>>>(qhb, Khb, Vth, Op0, Op1, Spart);
  attn_combine<<<(NS * HE) / 2048, 256, 0, stream>>>(Op0, Op1, Spart, attnh);
  gemm_f16<float><<<512, 256, 0, stream>>>(attnh, Wdt, bd, out, E, HE, 0.125f);
}

// Round 19
// 114.047 us; speedup vs baseline: 1.0594x; 1.0324x over previous
//
#include <hip/hip_runtime.h>

typedef _Float16 half8 __attribute__((ext_vector_type(8)));
typedef _Float16 half4v __attribute__((ext_vector_type(4)));
typedef __fp16 fp16x2 __attribute__((ext_vector_type(2)));
typedef float f32x4 __attribute__((ext_vector_type(4)));
typedef float f32x16 __attribute__((ext_vector_type(16)));
typedef float float4v __attribute__((ext_vector_type(4)));
typedef unsigned uint32x2 __attribute__((ext_vector_type(2)));

constexpr int NS = 4096;   // B*S rows
constexpr int E  = 1024;
constexpr int H  = 16;
constexpr int HD = 64;
constexpr int M  = 2048;
constexpr int HE = 1024;   // H*HD

__device__ __forceinline__ void gload16(const _Float16* g, _Float16* l) {
  __builtin_amdgcn_global_load_lds((__attribute__((address_space(1))) void*)g,
                                   (__attribute__((address_space(3))) void*)l, 16, 0, 0);
}

__device__ __forceinline__ float fexp2(float x) {
#if __has_builtin(__builtin_amdgcn_exp2f)
  return __builtin_amdgcn_exp2f(x);
#else
  return __expf(x * 0.6931471805599453f);
#endif
}

// pack two f32 -> one dword of 2 fp16 (RTZ)
__device__ __forceinline__ unsigned pkh(float a, float b) {
  fp16x2 t = __builtin_amdgcn_cvt_pkrtz(a, b);
  return __builtin_bit_cast(unsigned, t);
}

// lane<->lane+32 half-exchange
__device__ __forceinline__ uint32x2 pl32swap(unsigned a, unsigned b) {
#if __has_builtin(__builtin_amdgcn_permlane32_swap)
  return __builtin_amdgcn_permlane32_swap(a, b, false, false);
#else
  unsigned sa = (unsigned)__shfl_xor((int)a, 32, 64);
  unsigned sb = (unsigned)__shfl_xor((int)b, 32, 64);
  uint32x2 r;
  r.x = (threadIdx.x & 32) ? sb : a;
  r.y = (threadIdx.x & 32) ? b : sa;
  return r;
#endif
}

__device__ __forceinline__ half8 mk8(unsigned a, unsigned b, unsigned c, unsigned d) {
  union { unsigned u[4]; half8 h; } t;
  t.u[0] = a; t.u[1] = b; t.u[2] = c; t.u[3] = d;
  return t.h;
}

// ---------------- prep mega-kernel ----------------
// All input conversions in ONE launch; flat block id selects the section.
//  S0 [0,4096):      cvt tensor (f32) -> th (f16), scale 1
//  S1 [4096,6144):   cvt Kp -> Khb, scale log2(e)
//  S2 [6144,8192):   transpose 1024x1024 Wq->Wqt / Wd->Wdt (z = lb>>10)
//  S3 [8192,10240):  per-head transpose Vp [2048x64] -> Vth [64x2048]
// Bodies identical to the r18-proven kernels; only coordinates are derived
// from the flat id. Each block takes exactly one branch (uniform syncs).

__global__ void prep_all(const float* __restrict__ tensor, _Float16* __restrict__ th,
                         const float* __restrict__ Kp, _Float16* __restrict__ Khb,
                         const float* __restrict__ Wq, _Float16* __restrict__ Wqt,
                         const float* __restrict__ Wd, _Float16* __restrict__ Wdt,
                         const float* __restrict__ Vp, _Float16* __restrict__ Vth) {
  __shared__ float tile[32][33];
  const int b = blockIdx.x;
  const int tid = threadIdx.x;

  if (b < 6144) {
    // elementwise cvt sections
    const float* in;
    _Float16* out;
    float scale;
    int i;
    if (b < 4096) {
      in = tensor; out = th; scale = 1.0f;
      i = (b * 256 + tid) * 4;
    } else {
      in = Kp; out = Khb; scale = 1.44269504088896f;
      i = ((b - 4096) * 256 + tid) * 4;
    }
    float4v v = *(const float4v*)(in + i);
    half4v o = { (_Float16)(v[0] * scale), (_Float16)(v[1] * scale),
                 (_Float16)(v[2] * scale), (_Float16)(v[3] * scale) };
    *(half4v*)(out + i) = o;
    return;
  }

  const int tx = tid & 31, ty = tid >> 5;  // 32 x 8
  if (b < 8192) {
    // 1024x1024 weight transpose (two sources)
    const int lb = b - 6144;
    const float* in = (lb >> 10) ? Wd : Wq;
    _Float16* out = (lb >> 10) ? Wdt : Wqt;
    const int rem = lb & 1023;
    const int c0 = (rem & 31) * 32, r0 = (rem >> 5) * 32;
#pragma unroll
    for (int i = 0; i < 4; ++i)
      tile[ty + 8 * i][tx] = in[(size_t)(r0 + ty + 8 * i) * 1024 + c0 + tx];
    __syncthreads();
#pragma unroll
    for (int i = 0; i < 4; ++i)
      out[(size_t)(c0 + ty + 8 * i) * 1024 + r0 + tx] = (_Float16)tile[tx][ty + 8 * i];
    return;
  }

  // V transpose: per head z, [2048][64] -> [64][2048]
  {
    const int lb = b - 8192;
    const int z = lb >> 7;             // head
    const int rem = lb & 127;
    const int c0 = (rem & 1) * 32;     // col-tile over C=64
    const int r0 = (rem >> 1) * 32;    // row-tile over R=2048
    const float* in = Vp + (size_t)z * 2048 * 64;
    _Float16* out = Vth + (size_t)z * 2048 * 64;
#pragma unroll
    for (int i = 0; i < 4; ++i)
      tile[ty + 8 * i][tx] = in[(size_t)(r0 + ty + 8 * i) * 64 + c0 + tx];
    __syncthreads();
#pragma unroll
    for (int i = 0; i < 4; ++i)
      out[(size_t)(c0 + ty + 8 * i) * 2048 + r0 + tx] = (_Float16)tile[tx][ty + 8 * i];
  }
}

// ---------------- GEMM: C[M][N] = A[M][K] * Bt[N][K]^T, fp32 acc ----------------
// (r16-proven) 128x64 tile, 4 waves (2x2), wave tile 64x32 (4x2 frags):
// 6 LDS b128 reads serve 8 MFMA per K-step. Single-sync dbuf. grid 512.

template <typename OUT_T>
__global__ __launch_bounds__(256, 4) void gemm_f16(
    const _Float16* __restrict__ A,   // [Mrows][K]
    const _Float16* __restrict__ Bt,  // [Ncols][K]
    const float* __restrict__ bias,   // [Ncols]
    OUT_T* __restrict__ C,            // [Mrows][Ncols]
    int Ncols, int K, float scale)
{
  __shared__ alignas(16) _Float16 Ab[2][8 * 512];  // 16 KB: 8 chunks of 16r x 32k
  __shared__ alignas(16) _Float16 Bb[2][4 * 512];  //  8 KB: 4 chunks
  const int tid = threadIdx.x;
  const int wave = tid >> 6, lane = tid & 63;
  const int l15 = lane & 15, l4 = lane >> 4;

  const int nwg = gridDim.x;
  int wg = (blockIdx.x & 7) * (nwg >> 3) + (blockIdx.x >> 3);  // XCD swizzle (nwg%8==0)
  const int nbn = Ncols >> 6;
  const int mblk = wg / nbn, nblk = wg % nbn;

  // wave w stages A chunks {w, w+4} and B chunk w
  const _Float16* aS0 = A  + (size_t)(mblk * 128 + wave * 16 + l15) * K + l4 * 8;
  const _Float16* aS1 = aS0 + (size_t)64 * K;
  const _Float16* bS  = Bt + (size_t)(nblk * 64 + wave * 16 + l15) * K + l4 * 8;
  _Float16* aD0a = &Ab[0][wave * 512];
  _Float16* aD0b = &Ab[0][(wave + 4) * 512];
  _Float16* aD1a = &Ab[1][wave * 512];
  _Float16* aD1b = &Ab[1][(wave + 4) * 512];
  _Float16* bD0  = &Bb[0][wave * 512];
  _Float16* bD1  = &Bb[1][wave * 512];

  const int wr = wave >> 1, wc = wave & 1;  // 2x2 wave grid, wave tile 64x32
  f32x4 acc[4][2];
#pragma unroll
  for (int i = 0; i < 4; ++i)
#pragma unroll
    for (int n = 0; n < 2; ++n) acc[i][n] = (f32x4){0.f, 0.f, 0.f, 0.f};

  gload16(aS0, aD0a);
  gload16(aS1, aD0b);
  gload16(bS, bD0);
  aS0 += 32; aS1 += 32; bS += 32;

  const int nk = K >> 5;
  for (int kt = 0; kt < nk; ++kt) {
    __syncthreads();   // own tile-kt loads drained + all waves' loads visible
    if (kt + 1 < nk) {
      gload16(aS0, (kt & 1) ? aD0a : aD1a);
      gload16(aS1, (kt & 1) ? aD0b : aD1b);
      gload16(bS,  (kt & 1) ? bD0  : bD1);
      aS0 += 32; aS1 += 32; bS += 32;
    }
    const _Float16* Ac = (kt & 1) ? &Ab[1][0] : &Ab[0][0];
    const _Float16* Bc = (kt & 1) ? &Bb[1][0] : &Bb[0][0];
    half8 af[4], bf[2];
#pragma unroll
    for (int i = 0; i < 4; ++i) af[i] = *(const half8*)(Ac + (wr * 4 + i) * 512 + lane * 8);
#pragma unroll
    for (int n = 0; n < 2; ++n) bf[n] = *(const half8*)(Bc + (wc * 2 + n) * 512 + lane * 8);
    __builtin_amdgcn_s_setprio(1);
#pragma unroll
    for (int i = 0; i < 4; ++i)
#pragma unroll
      for (int n = 0; n < 2; ++n)
        acc[i][n] = __builtin_amdgcn_mfma_f32_16x16x32_f16(af[i], bf[n], acc[i][n], 0, 0, 0);
    __builtin_amdgcn_s_setprio(0);
  }

  const int row0 = mblk * 128 + wr * 64;
  const int col0 = nblk * 64 + wc * 32;
#pragma unroll
  for (int n = 0; n < 2; ++n) {
    int col = col0 + n * 16 + l15;
    float bv = bias[col];
#pragma unroll
    for (int i = 0; i < 4; ++i)
#pragma unroll
      for (int r = 0; r < 4; ++r) {
        int row = row0 + i * 16 + l4 * 4 + r;
        C[(size_t)row * Ncols + col] = (OUT_T)(acc[i][n][r] * scale + bv);
      }
  }
}

// ---------------- fused attention (M-split x2, 64 q/wave, in-register P) --------
// (byte-identical to r13/r16/r18 — best measured 51.7 us; frozen)

__global__ __launch_bounds__(256, 2) void attn_fused(
    const _Float16* __restrict__ qh,    // [NS][HE]
    const _Float16* __restrict__ Kh,    // [H][M][HD]  (pre-scaled by log2 e)
    const _Float16* __restrict__ Vth,   // [H][HD][M]
    _Float16* __restrict__ Op0,         // [NS][HE] partial sum pV, half 0
    _Float16* __restrict__ Op1,         // [NS][HE] partial sum pV, half 1
    float* __restrict__ Spart)          // [2][NS][H] partial sum p
{
  __shared__ alignas(16) _Float16 Kb[2][4096];  // 16 KB: 2 subtiles x (32m x 64d)
  __shared__ alignas(16) _Float16 Vb[2][4096];  // 16 KB: 2 subtiles x (64d x 32m)

  int wg = (blockIdx.x & 7) * 64 + (blockIdx.x >> 3);  // 2 heads per XCD
  const int h = wg >> 5, half = (wg >> 4) & 1, qblk = wg & 15;
  const int m0 = half * 1024;
  const int tid = threadIdx.x;
  const int wave = tid >> 6, lane = tid & 63;
  const int l31 = lane & 31, hi = lane >> 5;
  const int s0 = qblk * 256 + wave * 64;

  // Q B-frags for both q-groups: lane holds Q[s0+g*32+l31][c*16 + hi*8 + j]
  half8 qf[2][4];
#pragma unroll
  for (int g = 0; g < 2; ++g) {
    const _Float16* qp = qh + (size_t)(s0 + g * 32 + l31) * HE + h * HD + hi * 8;
    qf[g][0] = *(const half8*)(qp);
    qf[g][1] = *(const half8*)(qp + 16);
    qf[g][2] = *(const half8*)(qp + 32);
    qf[g][3] = *(const half8*)(qp + 48);
  }

  const _Float16* kS = Kh + (size_t)h * M * HD
                       + (size_t)((wave >> 1) * 32 + l31) * HD + (wave & 1) * 32 + hi * 8;
  const _Float16* vS = Vth + (size_t)(h * HD + (wave & 1) * 32 + l31) * M
                       + (wave >> 1) * 32 + hi * 8;
  const int dOff = wave * 1024 + lane * 8;

  f32x16 accA[2], accB[2];
  float lsum[2] = {0.f, 0.f};
#pragma unroll
  for (int g = 0; g < 2; ++g) {
    accA[g] = (f32x16){0.f,0.f,0.f,0.f,0.f,0.f,0.f,0.f,0.f,0.f,0.f,0.f,0.f,0.f,0.f,0.f};
    accB[g] = (f32x16){0.f,0.f,0.f,0.f,0.f,0.f,0.f,0.f,0.f,0.f,0.f,0.f,0.f,0.f,0.f,0.f};
  }

#define STAGE(b, mm) {                                        \
    gload16(kS + (size_t)(mm) * HD,      &Kb[b][dOff]);       \
    gload16(kS + (size_t)(mm) * HD + 16, &Kb[b][dOff + 512]); \
    gload16(vS + (mm),                   &Vb[b][dOff]);       \
    gload16(vS + (mm) + 16,              &Vb[b][dOff + 512]); }

  STAGE(0, m0);
  for (int kt = 0; kt < 16; ++kt) {
    const int cur = kt & 1;
    __syncthreads();   // own tile-kt loads drained + all waves' loads visible
    if (kt < 15) STAGE(cur ^ 1, m0 + (kt + 1) * 64);

    const _Float16* Kc = &Kb[cur][0];
    const _Float16* Vc = &Vb[cur][0];
    half8 kf[8];
#pragma unroll
    for (int c = 0; c < 8; ++c) kf[c] = *(const half8*)(Kc + c * 512 + lane * 8);

    half8 paA0[2], paA1[2], paB0[2], paB1[2];
#pragma unroll
    for (int g = 0; g < 2; ++g) {
      f32x16 sA = (f32x16){0.f,0.f,0.f,0.f,0.f,0.f,0.f,0.f,0.f,0.f,0.f,0.f,0.f,0.f,0.f,0.f};
      f32x16 sB = sA;
      __builtin_amdgcn_s_setprio(1);
#pragma unroll
      for (int c = 0; c < 4; ++c)
        sA = __builtin_amdgcn_mfma_f32_32x32x16_f16(kf[c], qf[g][c], sA, 0, 0, 0);
#pragma unroll
      for (int c = 0; c < 4; ++c)
        sB = __builtin_amdgcn_mfma_f32_32x32x16_f16(kf[4 + c], qf[g][c], sB, 0, 0, 0);
      __builtin_amdgcn_s_setprio(0);

      unsigned pdA[8], pdB[8];
      float la = 0.f;
#pragma unroll
      for (int i = 0; i < 8; ++i) {
        float a0 = fexp2(sA[2 * i]);
        float a1 = fexp2(sA[2 * i + 1]);
        float b0 = fexp2(sB[2 * i]);
        float b1 = fexp2(sB[2 * i + 1]);
        la += (a0 + a1) + (b0 + b1);
        pdA[i] = pkh(a0, a1);
        pdB[i] = pkh(b0, b1);
      }
      lsum[g] += la;
      uint32x2 wA0 = pl32swap(pdA[0], pdA[2]);
      uint32x2 wA1 = pl32swap(pdA[1], pdA[3]);
      uint32x2 wA2 = pl32swap(pdA[4], pdA[6]);
      uint32x2 wA3 = pl32swap(pdA[5], pdA[7]);
      paA0[g] = mk8(wA0.x, wA1.x, wA0.y, wA1.y);
      paA1[g] = mk8(wA2.x, wA3.x, wA2.y, wA3.y);
      uint32x2 wB0 = pl32swap(pdB[0], pdB[2]);
      uint32x2 wB1 = pl32swap(pdB[1], pdB[3]);
      uint32x2 wB2 = pl32swap(pdB[4], pdB[6]);
      uint32x2 wB3 = pl32swap(pdB[5], pdB[7]);
      paB0[g] = mk8(wB0.x, wB1.x, wB0.y, wB1.y);
      paB1[g] = mk8(wB2.x, wB3.x, wB2.y, wB3.y);
    }

    // PV: V chunks read once, used by both q-groups
    {
      half8 v0 = *(const half8*)(Vc + lane * 8);
      half8 v1 = *(const half8*)(Vc + 512 + lane * 8);
      half8 v2 = *(const half8*)(Vc + 1024 + lane * 8);
      half8 v3 = *(const half8*)(Vc + 1536 + lane * 8);
      __builtin_amdgcn_s_setprio(1);
#pragma unroll
      for (int g = 0; g < 2; ++g) {
        accA[g] = __builtin_amdgcn_mfma_f32_32x32x16_f16(paA0[g], v0, accA[g], 0, 0, 0);
        accA[g] = __builtin_amdgcn_mfma_f32_32x32x16_f16(paA1[g], v1, accA[g], 0, 0, 0);
        accB[g] = __builtin_amdgcn_mfma_f32_32x32x16_f16(paA0[g], v2, accB[g], 0, 0, 0);
        accB[g] = __builtin_amdgcn_mfma_f32_32x32x16_f16(paA1[g], v3, accB[g], 0, 0, 0);
      }
      __builtin_amdgcn_s_setprio(0);
    }
    {
      half8 v0 = *(const half8*)(Vc + 2048 + lane * 8);
      half8 v1 = *(const half8*)(Vc + 2560 + lane * 8);
      half8 v2 = *(const half8*)(Vc + 3072 + lane * 8);
      half8 v3 = *(const half8*)(Vc + 3584 + lane * 8);
      __builtin_amdgcn_s_setprio(1);
#pragma unroll
      for (int g = 0; g < 2; ++g) {
        accA[g] = __builtin_amdgcn_mfma_f32_32x32x16_f16(paB0[g], v0, accA[g], 0, 0, 0);
        accA[g] = __builtin_amdgcn_mfma_f32_32x32x16_f16(paB1[g], v1, accA[g], 0, 0, 0);
        accB[g] = __builtin_amdgcn_mfma_f32_32x32x16_f16(paB0[g], v2, accB[g], 0, 0, 0);
        accB[g] = __builtin_amdgcn_mfma_f32_32x32x16_f16(paB1[g], v3, accB[g], 0, 0, 0);
      }
      __builtin_amdgcn_s_setprio(0);
    }
  }
#undef STAGE

  _Float16* Op = half ? Op1 : Op0;
  float* Sp = Spart + (size_t)half * (NS * H);
#pragma unroll
  for (int g = 0; g < 2; ++g) {
#pragma unroll
    for (int r = 0; r < 16; ++r) {
      int q = s0 + g * 32 + (r & 3) + 8 * (r >> 2) + 4 * hi;
      Op[(size_t)q * HE + h * HD + l31]      = (_Float16)accA[g][r];
      Op[(size_t)q * HE + h * HD + 32 + l31] = (_Float16)accB[g][r];
    }
    float tot = lsum[g] + __shfl_xor(lsum[g], 32, 64);
    if (hi == 0) Sp[(size_t)(s0 + g * 32 + l31) * H + h] = tot;
  }
}

// combine: attnh = (O0 + O1) / (S0 + S1)
__global__ void attn_combine(const _Float16* __restrict__ O0, const _Float16* __restrict__ O1,
                             const float* __restrict__ Spart, _Float16* __restrict__ out) {
  int idx = (blockIdx.x * 256 + threadIdx.x) * 8;
  int row = idx >> 10, he = idx & 1023, h = he >> 6;
  half8 a = *(const half8*)(O0 + idx);
  half8 b = *(const half8*)(O1 + idx);
  float s = Spart[(size_t)row * H + h] + Spart[(size_t)(NS + row) * H + h];
  float inv = 1.0f / s;
  half8 o;
#pragma unroll
  for (int j = 0; j < 8; ++j) o[j] = (_Float16)(((float)a[j] + (float)b[j]) * inv);
  *(half8*)(out + idx) = o;
}

// ---------------- launch ----------------

extern "C" void kernel_launch(void* const* d_in, const int* in_sizes, int n_in,
                              void* d_out, int out_size, void* d_ws, size_t ws_size,
                              hipStream_t stream) {
  const float* tensor = (const float*)d_in[0];
  const float* Wq     = (const float*)d_in[1];
  const float* bq     = (const float*)d_in[2];
  const float* Kp     = (const float*)d_in[3];
  const float* Vp     = (const float*)d_in[4];
  const float* Wd     = (const float*)d_in[5];
  const float* bd     = (const float*)d_in[6];
  float* out = (float*)d_out;

  char* ws = (char*)d_ws;
  _Float16* th    = (_Float16*)(ws);                  // [4096][1024] 8 MB; reused as Op0
  _Float16* qhb   = (_Float16*)(ws + (8  << 20));     // 8 MB
  _Float16* attnh = (_Float16*)(ws + (16 << 20));     // 8 MB
  _Float16* Wqt   = (_Float16*)(ws + (24 << 20));     // 2 MB; reused as Spart after gemm1
  _Float16* Wdt   = (_Float16*)(ws + (26 << 20));     // 2 MB
  _Float16* Khb   = (_Float16*)(ws + (28 << 20));     // 4 MB
  _Float16* Vth   = (_Float16*)(ws + (32 << 20));     // 4 MB
  _Float16* Op0   = (_Float16*)(ws);                  // overlays th (dead after gemm1)
  _Float16* Op1   = (_Float16*)(ws + (36 << 20));     // 8 MB  (total 44 MB)
  float*    Spart = (float*)(ws + (24 << 20));        // [2][4096][16] f32, overlays Wqt

  prep_all<<<10240, 256, 0, stream>>>(tensor, th, Kp, Khb, Wq, Wqt, Wd, Wdt, Vp, Vth);

  gemm_f16<_Float16><<<512, 256, 0, stream>>>(th, Wqt, bq, qhb, HE, E, 1.0f);
  attn_fused<<<512, 256, 0, stream>>>(qhb, Khb, Vth, Op0, Op1, Spart);
  attn_combine<<<(NS * HE) / 2048, 256, 0, stream>>>(Op0, Op1, Spart, attnh);
  gemm_f16<float><<<512, 256, 0, stream>>>(attnh, Wdt, bd, out, E, HE, 0.125f);
}

// Round 20
// 113.426 us; speedup vs baseline: 1.0652x; 1.0055x over previous
//
#include <hip/hip_runtime.h>

typedef _Float16 half8 __attribute__((ext_vector_type(8)));
typedef _Float16 half4v __attribute__((ext_vector_type(4)));
typedef __fp16 fp16x2 __attribute__((ext_vector_type(2)));
typedef float f32x4 __attribute__((ext_vector_type(4)));
typedef float f32x16 __attribute__((ext_vector_type(16)));
typedef float float4v __attribute__((ext_vector_type(4)));
typedef unsigned uint32x2 __attribute__((ext_vector_type(2)));

constexpr int NS = 4096;   // B*S rows
constexpr int E  = 1024;
constexpr int H  = 16;
constexpr int HD = 64;
constexpr int M  = 2048;
constexpr int HE = 1024;   // H*HD

__device__ __forceinline__ void gload16(const _Float16* g, _Float16* l) {
  __builtin_amdgcn_global_load_lds((__attribute__((address_space(1))) void*)g,
                                   (__attribute__((address_space(3))) void*)l, 16, 0, 0);
}

__device__ __forceinline__ float fexp2(float x) {
#if __has_builtin(__builtin_amdgcn_exp2f)
  return __builtin_amdgcn_exp2f(x);
#else
  return __expf(x * 0.6931471805599453f);
#endif
}

// pack two f32 -> one dword of 2 fp16 (RTZ)
__device__ __forceinline__ unsigned pkh(float a, float b) {
  fp16x2 t = __builtin_amdgcn_cvt_pkrtz(a, b);
  return __builtin_bit_cast(unsigned, t);
}

// lane<->lane+32 half-exchange
__device__ __forceinline__ uint32x2 pl32swap(unsigned a, unsigned b) {
#if __has_builtin(__builtin_amdgcn_permlane32_swap)
  return __builtin_amdgcn_permlane32_swap(a, b, false, false);
#else
  unsigned sa = (unsigned)__shfl_xor((int)a, 32, 64);
  unsigned sb = (unsigned)__shfl_xor((int)b, 32, 64);
  uint32x2 r;
  r.x = (threadIdx.x & 32) ? sb : a;
  r.y = (threadIdx.x & 32) ? b : sa;
  return r;
#endif
}

__device__ __forceinline__ half8 mk8(unsigned a, unsigned b, unsigned c, unsigned d) {
  union { unsigned u[4]; half8 h; } t;
  t.u[0] = a; t.u[1] = b; t.u[2] = c; t.u[3] = d;
  return t.h;
}

// ---------------- prep mega-kernel (r19-proven) ----------------

__global__ void prep_all(const float* __restrict__ tensor, _Float16* __restrict__ th,
                         const float* __restrict__ Kp, _Float16* __restrict__ Khb,
                         const float* __restrict__ Wq, _Float16* __restrict__ Wqt,
                         const float* __restrict__ Wd, _Float16* __restrict__ Wdt,
                         const float* __restrict__ Vp, _Float16* __restrict__ Vth) {
  __shared__ float tile[32][33];
  const int b = blockIdx.x;
  const int tid = threadIdx.x;

  if (b < 6144) {
    const float* in;
    _Float16* out;
    float scale;
    int i;
    if (b < 4096) {
      in = tensor; out = th; scale = 1.0f;
      i = (b * 256 + tid) * 4;
    } else {
      in = Kp; out = Khb; scale = 1.44269504088896f;
      i = ((b - 4096) * 256 + tid) * 4;
    }
    float4v v = *(const float4v*)(in + i);
    half4v o = { (_Float16)(v[0] * scale), (_Float16)(v[1] * scale),
                 (_Float16)(v[2] * scale), (_Float16)(v[3] * scale) };
    *(half4v*)(out + i) = o;
    return;
  }

  const int tx = tid & 31, ty = tid >> 5;  // 32 x 8
  if (b < 8192) {
    const int lb = b - 6144;
    const float* in = (lb >> 10) ? Wd : Wq;
    _Float16* out = (lb >> 10) ? Wdt : Wqt;
    const int rem = lb & 1023;
    const int c0 = (rem & 31) * 32, r0 = (rem >> 5) * 32;
#pragma unroll
    for (int i = 0; i < 4; ++i)
      tile[ty + 8 * i][tx] = in[(size_t)(r0 + ty + 8 * i) * 1024 + c0 + tx];
    __syncthreads();
#pragma unroll
    for (int i = 0; i < 4; ++i)
      out[(size_t)(c0 + ty + 8 * i) * 1024 + r0 + tx] = (_Float16)tile[tx][ty + 8 * i];
    return;
  }

  {
    const int lb = b - 8192;
    const int z = lb >> 7;             // head
    const int rem = lb & 127;
    const int c0 = (rem & 1) * 32;     // col-tile over C=64
    const int r0 = (rem >> 1) * 32;    // row-tile over R=2048
    const float* in = Vp + (size_t)z * 2048 * 64;
    _Float16* out = Vth + (size_t)z * 2048 * 64;
#pragma unroll
    for (int i = 0; i < 4; ++i)
      tile[ty + 8 * i][tx] = in[(size_t)(r0 + ty + 8 * i) * 64 + c0 + tx];
    __syncthreads();
#pragma unroll
    for (int i = 0; i < 4; ++i)
      out[(size_t)(c0 + ty + 8 * i) * 2048 + r0 + tx] = (_Float16)tile[tx][ty + 8 * i];
  }
}

// ---------------- GEMM: C[M][N] = A[M][K] * Bt[N][K]^T, fp32 acc ----------------
// r16 structure with BK=64: two 32-k halves per barrier round (16 syncs vs 32).
// Same chunk geometry (16r x 32k frag-contiguous), 6 gload16/wave/iter,
// per-half frags reuse registers. LDS 48 KB; grid 512 (2 blocks/CU unchanged).

template <typename OUT_T>
__global__ __launch_bounds__(256, 4) void gemm_f16(
    const _Float16* __restrict__ A,   // [Mrows][K]
    const _Float16* __restrict__ Bt,  // [Ncols][K]
    const float* __restrict__ bias,   // [Ncols]
    OUT_T* __restrict__ C,            // [Mrows][Ncols]
    int Ncols, int K, float scale)
{
  __shared__ alignas(16) _Float16 Ab[2][2][8 * 512];  // 32 KB: [buf][khalf][chunk]
  __shared__ alignas(16) _Float16 Bb[2][2][4 * 512];  // 16 KB
  const int tid = threadIdx.x;
  const int wave = tid >> 6, lane = tid & 63;
  const int l15 = lane & 15, l4 = lane >> 4;

  const int nwg = gridDim.x;
  int wg = (blockIdx.x & 7) * (nwg >> 3) + (blockIdx.x >> 3);  // XCD swizzle (nwg%8==0)
  const int nbn = Ncols >> 6;
  const int mblk = wg / nbn, nblk = wg % nbn;

  // wave w stages A chunks {w, w+4} and B chunk w, both k-halves
  const _Float16* aS0 = A  + (size_t)(mblk * 128 + wave * 16 + l15) * K + l4 * 8;
  const _Float16* aS1 = aS0 + (size_t)64 * K;
  const _Float16* bS  = Bt + (size_t)(nblk * 64 + wave * 16 + l15) * K + l4 * 8;

  const int wr = wave >> 1, wc = wave & 1;  // 2x2 wave grid, wave tile 64x32
  f32x4 acc[4][2];
#pragma unroll
  for (int i = 0; i < 4; ++i)
#pragma unroll
    for (int n = 0; n < 2; ++n) acc[i][n] = (f32x4){0.f, 0.f, 0.f, 0.f};

#define GSTAGE(b, kk) {                                              \
    gload16(aS0 + (kk),      &Ab[b][0][wave * 512 + lane * 8] - lane * 8 + wave * 512); \
    gload16(aS0 + (kk) + 32, &Ab[b][1][wave * 512]);                 \
    gload16(aS1 + (kk),      &Ab[b][0][(wave + 4) * 512]);           \
    gload16(aS1 + (kk) + 32, &Ab[b][1][(wave + 4) * 512]);           \
    gload16(bS + (kk),       &Bb[b][0][wave * 512]);                 \
    gload16(bS + (kk) + 32,  &Bb[b][1][wave * 512]); }

// fix first line of macro (plain form)
#undef GSTAGE
#define GSTAGE(b, kk) {                                    \
    gload16(aS0 + (kk),      &Ab[b][0][wave * 512]);       \
    gload16(aS0 + (kk) + 32, &Ab[b][1][wave * 512]);       \
    gload16(aS1 + (kk),      &Ab[b][0][(wave + 4) * 512]); \
    gload16(aS1 + (kk) + 32, &Ab[b][1][(wave + 4) * 512]); \
    gload16(bS + (kk),       &Bb[b][0][wave * 512]);       \
    gload16(bS + (kk) + 32,  &Bb[b][1][wave * 512]); }

  GSTAGE(0, 0);
  const int nk = K >> 6;
  for (int kt = 0; kt < nk; ++kt) {
    __syncthreads();   // own tile-kt loads drained + all waves' loads visible
    if (kt + 1 < nk) GSTAGE((kt + 1) & 1, (kt + 1) * 64);
    const int buf = kt & 1;
#pragma unroll
    for (int s = 0; s < 2; ++s) {
      const _Float16* Ac = &Ab[buf][s][0];
      const _Float16* Bc = &Bb[buf][s][0];
      half8 af[4], bf[2];
#pragma unroll
      for (int i = 0; i < 4; ++i) af[i] = *(const half8*)(Ac + (wr * 4 + i) * 512 + lane * 8);
#pragma unroll
      for (int n = 0; n < 2; ++n) bf[n] = *(const half8*)(Bc + (wc * 2 + n) * 512 + lane * 8);
      __builtin_amdgcn_s_setprio(1);
#pragma unroll
      for (int i = 0; i < 4; ++i)
#pragma unroll
        for (int n = 0; n < 2; ++n)
          acc[i][n] = __builtin_amdgcn_mfma_f32_16x16x32_f16(af[i], bf[n], acc[i][n], 0, 0, 0);
      __builtin_amdgcn_s_setprio(0);
    }
  }
#undef GSTAGE

  const int row0 = mblk * 128 + wr * 64;
  const int col0 = nblk * 64 + wc * 32;
#pragma unroll
  for (int n = 0; n < 2; ++n) {
    int col = col0 + n * 16 + l15;
    float bv = bias[col];
#pragma unroll
    for (int i = 0; i < 4; ++i)
#pragma unroll
      for (int r = 0; r < 4; ++r) {
        int row = row0 + i * 16 + l4 * 4 + r;
        C[(size_t)row * Ncols + col] = (OUT_T)(acc[i][n][r] * scale + bv);
      }
  }
}

// ---------------- fused attention (M-split x2, 64 q/wave, in-register P) --------
// (byte-identical to r13/r16/r19 — best measured 51.7 us; frozen)

__global__ __launch_bounds__(256, 2) void attn_fused(
    const _Float16* __restrict__ qh,    // [NS][HE]
    const _Float16* __restrict__ Kh,    // [H][M][HD]  (pre-scaled by log2 e)
    const _Float16* __restrict__ Vth,   // [H][HD][M]
    _Float16* __restrict__ Op0,         // [NS][HE] partial sum pV, half 0
    _Float16* __restrict__ Op1,         // [NS][HE] partial sum pV, half 1
    float* __restrict__ Spart)          // [2][NS][H] partial sum p
{
  __shared__ alignas(16) _Float16 Kb[2][4096];  // 16 KB: 2 subtiles x (32m x 64d)
  __shared__ alignas(16) _Float16 Vb[2][4096];  // 16 KB: 2 subtiles x (64d x 32m)

  int wg = (blockIdx.x & 7) * 64 + (blockIdx.x >> 3);  // 2 heads per XCD
  const int h = wg >> 5, half = (wg >> 4) & 1, qblk = wg & 15;
  const int m0 = half * 1024;
  const int tid = threadIdx.x;
  const int wave = tid >> 6, lane = tid & 63;
  const int l31 = lane & 31, hi = lane >> 5;
  const int s0 = qblk * 256 + wave * 64;

  // Q B-frags for both q-groups: lane holds Q[s0+g*32+l31][c*16 + hi*8 + j]
  half8 qf[2][4];
#pragma unroll
  for (int g = 0; g < 2; ++g) {
    const _Float16* qp = qh + (size_t)(s0 + g * 32 + l31) * HE + h * HD + hi * 8;
    qf[g][0] = *(const half8*)(qp);
    qf[g][1] = *(const half8*)(qp + 16);
    qf[g][2] = *(const half8*)(qp + 32);
    qf[g][3] = *(const half8*)(qp + 48);
  }

  const _Float16* kS = Kh + (size_t)h * M * HD
                       + (size_t)((wave >> 1) * 32 + l31) * HD + (wave & 1) * 32 + hi * 8;
  const _Float16* vS = Vth + (size_t)(h * HD + (wave & 1) * 32 + l31) * M
                       + (wave >> 1) * 32 + hi * 8;
  const int dOff = wave * 1024 + lane * 8;

  f32x16 accA[2], accB[2];
  float lsum[2] = {0.f, 0.f};
#pragma unroll
  for (int g = 0; g < 2; ++g) {
    accA[g] = (f32x16){0.f,0.f,0.f,0.f,0.f,0.f,0.f,0.f,0.f,0.f,0.f,0.f,0.f,0.f,0.f,0.f};
    accB[g] = (f32x16){0.f,0.f,0.f,0.f,0.f,0.f,0.f,0.f,0.f,0.f,0.f,0.f,0.f,0.f,0.f,0.f};
  }

#define STAGE(b, mm) {                                        \
    gload16(kS + (size_t)(mm) * HD,      &Kb[b][dOff]);       \
    gload16(kS + (size_t)(mm) * HD + 16, &Kb[b][dOff + 512]); \
    gload16(vS + (mm),                   &Vb[b][dOff]);       \
    gload16(vS + (mm) + 16,              &Vb[b][dOff + 512]); }

  STAGE(0, m0);
  for (int kt = 0; kt < 16; ++kt) {
    const int cur = kt & 1;
    __syncthreads();   // own tile-kt loads drained + all waves' loads visible
    if (kt < 15) STAGE(cur ^ 1, m0 + (kt + 1) * 64);

    const _Float16* Kc = &Kb[cur][0];
    const _Float16* Vc = &Vb[cur][0];
    half8 kf[8];
#pragma unroll
    for (int c = 0; c < 8; ++c) kf[c] = *(const half8*)(Kc + c * 512 + lane * 8);

    half8 paA0[2], paA1[2], paB0[2], paB1[2];
#pragma unroll
    for (int g = 0; g < 2; ++g) {
      f32x16 sA = (f32x16){0.f,0.f,0.f,0.f,0.f,0.f,0.f,0.f,0.f,0.f,0.f,0.f,0.f,0.f,0.f,0.f};
      f32x16 sB = sA;
      __builtin_amdgcn_s_setprio(1);
#pragma unroll
      for (int c = 0; c < 4; ++c)
        sA = __builtin_amdgcn_mfma_f32_32x32x16_f16(kf[c], qf[g][c], sA, 0, 0, 0);
#pragma unroll
      for (int c = 0; c < 4; ++c)
        sB = __builtin_amdgcn_mfma_f32_32x32x16_f16(kf[4 + c], qf[g][c], sB, 0, 0, 0);
      __builtin_amdgcn_s_setprio(0);

      unsigned pdA[8], pdB[8];
      float la = 0.f;
#pragma unroll
      for (int i = 0; i < 8; ++i) {
        float a0 = fexp2(sA[2 * i]);
        float a1 = fexp2(sA[2 * i + 1]);
        float b0 = fexp2(sB[2 * i]);
        float b1 = fexp2(sB[2 * i + 1]);
        la += (a0 + a1) + (b0 + b1);
        pdA[i] = pkh(a0, a1);
        pdB[i] = pkh(b0, b1);
      }
      lsum[g] += la;
      uint32x2 wA0 = pl32swap(pdA[0], pdA[2]);
      uint32x2 wA1 = pl32swap(pdA[1], pdA[3]);
      uint32x2 wA2 = pl32swap(pdA[4], pdA[6]);
      uint32x2 wA3 = pl32swap(pdA[5], pdA[7]);
      paA0[g] = mk8(wA0.x, wA1.x, wA0.y, wA1.y);
      paA1[g] = mk8(wA2.x, wA3.x, wA2.y, wA3.y);
      uint32x2 wB0 = pl32swap(pdB[0], pdB[2]);
      uint32x2 wB1 = pl32swap(pdB[1], pdB[3]);
      uint32x2 wB2 = pl32swap(pdB[4], pdB[6]);
      uint32x2 wB3 = pl32swap(pdB[5], pdB[7]);
      paB0[g] = mk8(wB0.x, wB1.x, wB0.y, wB1.y);
      paB1[g] = mk8(wB2.x, wB3.x, wB2.y, wB3.y);
    }

    // PV: V chunks read once, used by both q-groups
    {
      half8 v0 = *(const half8*)(Vc + lane * 8);
      half8 v1 = *(const half8*)(Vc + 512 + lane * 8);
      half8 v2 = *(const half8*)(Vc + 1024 + lane * 8);
      half8 v3 = *(const half8*)(Vc + 1536 + lane * 8);
      __builtin_amdgcn_s_setprio(1);
#pragma unroll
      for (int g = 0; g < 2; ++g) {
        accA[g] = __builtin_amdgcn_mfma_f32_32x32x16_f16(paA0[g], v0, accA[g], 0, 0, 0);
        accA[g] = __builtin_amdgcn_mfma_f32_32x32x16_f16(paA1[g], v1, accA[g], 0, 0, 0);
        accB[g] = __builtin_amdgcn_mfma_f32_32x32x16_f16(paA0[g], v2, accB[g], 0, 0, 0);
        accB[g] = __builtin_amdgcn_mfma_f32_32x32x16_f16(paA1[g], v3, accB[g], 0, 0, 0);
      }
      __builtin_amdgcn_s_setprio(0);
    }
    {
      half8 v0 = *(const half8*)(Vc + 2048 + lane * 8);
      half8 v1 = *(const half8*)(Vc + 2560 + lane * 8);
      half8 v2 = *(const half8*)(Vc + 3072 + lane * 8);
      half8 v3 = *(const half8*)(Vc + 3584 + lane * 8);
      __builtin_amdgcn_s_setprio(1);
#pragma unroll
      for (int g = 0; g < 2; ++g) {
        accA[g] = __builtin_amdgcn_mfma_f32_32x32x16_f16(paB0[g], v0, accA[g], 0, 0, 0);
        accA[g] = __builtin_amdgcn_mfma_f32_32x32x16_f16(paB1[g], v1, accA[g], 0, 0, 0);
        accB[g] = __builtin_amdgcn_mfma_f32_32x32x16_f16(paB0[g], v2, accB[g], 0, 0, 0);
        accB[g] = __builtin_amdgcn_mfma_f32_32x32x16_f16(paB1[g], v3, accB[g], 0, 0, 0);
      }
      __builtin_amdgcn_s_setprio(0);
    }
  }
#undef STAGE

  _Float16* Op = half ? Op1 : Op0;
  float* Sp = Spart + (size_t)half * (NS * H);
#pragma unroll
  for (int g = 0; g < 2; ++g) {
#pragma unroll
    for (int r = 0; r < 16; ++r) {
      int q = s0 + g * 32 + (r & 3) + 8 * (r >> 2) + 4 * hi;
      Op[(size_t)q * HE + h * HD + l31]      = (_Float16)accA[g][r];
      Op[(size_t)q * HE + h * HD + 32 + l31] = (_Float16)accB[g][r];
    }
    float tot = lsum[g] + __shfl_xor(lsum[g], 32, 64);
    if (hi == 0) Sp[(size_t)(s0 + g * 32 + l31) * H + h] = tot;
  }
}

// combine: attnh = (O0 + O1) / (S0 + S1)
__global__ void attn_combine(const _Float16* __restrict__ O0, const _Float16* __restrict__ O1,
                             const float* __restrict__ Spart, _Float16* __restrict__ out) {
  int idx = (blockIdx.x * 256 + threadIdx.x) * 8;
  int row = idx >> 10, he = idx & 1023, h = he >> 6;
  half8 a = *(const half8*)(O0 + idx);
  half8 b = *(const half8*)(O1 + idx);
  float s = Spart[(size_t)row * H + h] + Spart[(size_t)(NS + row) * H + h];
  float inv = 1.0f / s;
  half8 o;
#pragma unroll
  for (int j = 0; j < 8; ++j) o[j] = (_Float16)(((float)a[j] + (float)b[j]) * inv);
  *(half8*)(out + idx) = o;
}

// ---------------- launch ----------------

extern "C" void kernel_launch(void* const* d_in, const int* in_sizes, int n_in,
                              void* d_out, int out_size, void* d_ws, size_t ws_size,
                              hipStream_t stream) {
  const float* tensor = (const float*)d_in[0];
  const float* Wq     = (const float*)d_in[1];
  const float* bq     = (const float*)d_in[2];
  const float* Kp     = (const float*)d_in[3];
  const float* Vp     = (const float*)d_in[4];
  const float* Wd     = (const float*)d_in[5];
  const float* bd     = (const float*)d_in[6];
  float* out = (float*)d_out;

  char* ws = (char*)d_ws;
  _Float16* th    = (_Float16*)(ws);                  // [4096][1024] 8 MB; reused as Op0
  _Float16* qhb   = (_Float16*)(ws + (8  << 20));     // 8 MB
  _Float16* attnh = (_Float16*)(ws + (16 << 20));     // 8 MB
  _Float16* Wqt   = (_Float16*)(ws + (24 << 20));     // 2 MB; reused as Spart after gemm1
  _Float16* Wdt   = (_Float16*)(ws + (26 << 20));     // 2 MB
  _Float16* Khb   = (_Float16*)(ws + (28 << 20));     // 4 MB
  _Float16* Vth   = (_Float16*)(ws + (32 << 20));     // 4 MB
  _Float16* Op0   = (_Float16*)(ws);                  // overlays th (dead after gemm1)
  _Float16* Op1   = (_Float16*)(ws + (36 << 20));     // 8 MB  (total 44 MB)
  float*    Spart = (float*)(ws + (24 << 20));        // [2][4096][16] f32, overlays Wqt

  prep_all<<<10240, 256, 0, stream>>>(tensor, th, Kp, Khb, Wq, Wqt, Wd, Wdt, Vp, Vth);

  gemm_f16<_Float16><<<512, 256, 0, stream>>>(th, Wqt, bq, qhb, HE, E, 1.0f);
  attn_fused<<<512, 256, 0, stream>>>(qhb, Khb, Vth, Op0, Op1, Spart);
  attn_combine<<<(NS * HE) / 2048, 256, 0, stream>>>(Op0, Op1, Spart, attnh);
  gemm_f16<float><<<512, 256, 0, stream>>>(attnh, Wdt, bd, out, E, HE, 0.125f);
}